// Round 6
// baseline (446.365 us; speedup 1.0000x reference)
//
#include <hip/hip_runtime.h>
#include <math.h>

// OFPenalty: power-iteration eigen-penalty on AAT = W W^T per batch, never
// materializing AAT. Round 8: pipelined-loop k_step at real occupancy.
//  - Evidence: every one-shot/burst variant pins at ~2.7-3.4 TB/s regardless
//    of layout or occupancy; the only faster variant (R3, 34us) was a
//    register-pipelined chunk loop, but grid-starved (1.75 blocks/CU).
//    Theory: one-shot waves have ~50% memory duty cycle (load burst, then
//    long serial compute with vmcnt drained); phase-locked blocks leave HBM
//    idle half the time.
//  - Fix: k_step = 16 blocks/batch (1024 blocks, 4/CU, launch_bounds(256,4)
//    -> 16 waves/CU), each wave loops quads q = s*4+w+64j (3-4 iters) with a
//    two-named-register-buffer software pipeline: compute(ra) overlaps the
//    in-flight loads of rb. All register indices static (no scratch).
//  - Normalize fused into k_step phase A (nparts partial segments).
//  - k_repack unchanged from R5 (60us known; next target if theory holds).
// A: (64, 512, 28, 28) fp32 -> W: (64, 512, 784). x0: (64, 512, 1).

#define BB 64
#define CC 512
#define DD 784
#define NSPLIT 16       // k_step blocks per batch; wave (s,w) owns quads s*4+w+64j
#define NQ 196          // f4-columns (quads) total
#define F4PR 196        // float4 per row of A
#define BF4 100352      // float4 per batch matrix (512*784/4)
#define QT 28           // f4-cols per repack tile
#define CBS 12544       // f4 per cb slab = 196*64
#define FEPS 1e-12f

__device__ __forceinline__ float blk_reduce(float s, float* red) {
    for (int off = 32; off; off >>= 1) s += __shfl_down(s, off, 64);
    int w = threadIdx.x >> 6;
    if ((threadIdx.x & 63) == 0) red[w] = s;
    __syncthreads();
    float t = red[0] + red[1] + red[2] + red[3];
    __syncthreads();                       // allow red[] reuse by caller
    return t;
}

// Repack A[b][c][d] -> T3[b][cb][chq][i], c = cb*64+i, chq = d>>2 (0..195).
// (unchanged from R5; 60us known cost)
__global__ __launch_bounds__(256, 5)
void k_repack(const float* __restrict__ A, float* __restrict__ T) {
    __shared__ float4 lds4[64 * QT];       // 28,672 B
    const int tid = threadIdx.x;
    const int b = blockIdx.y, tile = blockIdx.x;
    const int cb = tile / 7, qt = tile % 7;
    const int R0 = cb * 64, q0 = qt * QT;
    const int r = tid >> 2, qg = tid & 3;
    const float4* src = (const float4*)A +
        ((size_t)b * CC + R0 + r) * F4PR + q0 + qg * 7;
    float4 a[7];
#pragma unroll
    for (int j = 0; j < 7; j++) a[j] = src[j];
    const int xr = (r >> 2) & 3;           // 2-bit XOR keeps chq' in 0..27
#pragma unroll
    for (int j = 0; j < 7; j++)
        lds4[r * QT + ((qg * 7 + j) ^ xr)] = a[j];
    __syncthreads();
    float4* dst = (float4*)T + (size_t)b * BF4 + (size_t)cb * CBS +
                  (size_t)q0 * 64;
#pragma unroll
    for (int j = 0; j < 7; j++) {
        int idx = j * 256 + tid;           // 0..1791 = 28 chq x 64 i
        int chq = idx >> 6, i = idx & 63;
        dst[idx] = lds4[i * QT + (chq ^ ((i >> 2) & 3))];
    }
}

// vout[b][s][c] = partial of (AAT_b * normalize(sum_p xin[b][p][:]))_c over
// wave-owned quads q = s*4+w+64j. Two-buffer register pipeline per wave.
template <bool RP>
__global__ __launch_bounds__(256, 4)
void k_step(const float* __restrict__ M, const float* __restrict__ xin,
            const int nparts, float* __restrict__ vout) {
    __shared__ float xs[CC];
    __shared__ float vws[4][CC];
    __shared__ float red[4];

    const int tid = threadIdx.x;
    const int b = blockIdx.y, s = blockIdx.x;
    const int lane = tid & 63, w = tid >> 6;
    const int q0 = s * 4 + w;              // 0..63
    const float4* Mb = (const float4*)M + (size_t)b * BF4;

    float xk[8];
    float vk[8] = {0.f, 0.f, 0.f, 0.f, 0.f, 0.f, 0.f, 0.f};

    auto loadq = [&](int q, float4* d) {
        if (RP) {
            const float4* g = Mb + (size_t)q * 64 + lane;
#pragma unroll
            for (int k = 0; k < 8; k++) d[k] = g[(size_t)k * CBS];
        } else {
            const float4* g = Mb + (size_t)lane * F4PR + q;
#pragma unroll
            for (int k = 0; k < 8; k++) d[k] = g[(size_t)64 * k * F4PR];
        }
    };
    auto computeq = [&](const float4* a) {
        float4 ua = make_float4(0.f, 0.f, 0.f, 0.f);
#pragma unroll
        for (int k = 0; k < 8; k++) {
            ua.x += a[k].x * xk[k]; ua.y += a[k].y * xk[k];
            ua.z += a[k].z * xk[k]; ua.w += a[k].w * xk[k];
        }
#pragma unroll
        for (int off = 1; off < 64; off <<= 1) {
            ua.x += __shfl_xor(ua.x, off, 64);
            ua.y += __shfl_xor(ua.y, off, 64);
            ua.z += __shfl_xor(ua.z, off, 64);
            ua.w += __shfl_xor(ua.w, off, 64);
        }
#pragma unroll
        for (int k = 0; k < 8; k++)
            vk[k] += a[k].x * ua.x + a[k].y * ua.y +
                     a[k].z * ua.z + a[k].w * ua.w;
    };

    // issue the first two quad tiles (16 x 1KB wave-contiguous loads)
    float4 ra[8], rb[8];
    loadq(q0, ra);
    loadq(q0 + 64, rb);                    // q0+64 <= 127 < 196 always

    // ---- phase A: normalize input (sum nparts partial segments)
    const float* xp = xin + (size_t)b * nparts * CC;
    float xv0 = 0.f, xv1 = 0.f;
    for (int p = 0; p < nparts; p++) {
        xv0 += xp[p * CC + tid];
        xv1 += xp[p * CC + tid + 256];
    }
    float ss = blk_reduce(xv0 * xv0 + xv1 * xv1, red);
    float rn = 1.0f / fmaxf(sqrtf(ss), FEPS);
    xs[tid] = xv0 * rn;
    xs[tid + 256] = xv1 * rn;
    __syncthreads();
#pragma unroll
    for (int k = 0; k < 8; k++) xk[k] = xs[lane + 64 * k];

    // ---- pipelined quad walk: compute(cur) overlaps other buffer's loads
    computeq(ra);                          // q0
    loadq(q0 + 128, ra);                   // q0+128 <= 191 < 196 always
    computeq(rb);                          // q0+64
    const bool has4 = (q0 + 192) < NQ;     // only s=0 waves (q0<4)
    if (has4) loadq(q0 + 192, rb);
    computeq(ra);                          // q0+128
    if (has4) computeq(rb);                // q0+192

    // ---- cross-wave quad sum
#pragma unroll
    for (int k = 0; k < 8; k++) vws[w][lane + 64 * k] = vk[k];
    __syncthreads();
    float* vp = vout + ((size_t)b * NSPLIT + s) * CC;
    vp[tid]       = vws[0][tid] + vws[1][tid] + vws[2][tid] + vws[3][tid];
    vp[tid + 256] = vws[0][tid + 256] + vws[1][tid + 256] +
                    vws[2][tid + 256] + vws[3][tid + 256];
}

// largest_b = <t5, x1>/<x1,x1>, x1 = t4/||t4||;  y = t5 - largest*x1
// t4, t5 are NSPLIT-way partial buffers [b][NSPLIT][512].
__global__ void k_mid(const float* __restrict__ t4, const float* __restrict__ t5,
                      float* __restrict__ acc, float* __restrict__ y) {
    __shared__ float red[4];
    int b = blockIdx.x;
    const float* p4 = t4 + (size_t)b * NSPLIT * CC;
    const float* p5 = t5 + (size_t)b * NSPLIT * CC;
    float a0 = 0.f, a1 = 0.f, b0 = 0.f, b1 = 0.f;
    for (int p = 0; p < NSPLIT; p++) {
        a0 += p4[p * CC + threadIdx.x]; a1 += p4[p * CC + threadIdx.x + 256];
        b0 += p5[p * CC + threadIdx.x]; b1 += p5[p * CC + threadIdx.x + 256];
    }
    float ss4 = blk_reduce(a0 * a0 + a1 * a1, red);
    float rn = 1.0f / fmaxf(sqrtf(ss4), FEPS);
    float x10 = a0 * rn, x11 = a1 * rn;
    float num = blk_reduce(b0 * x10 + b1 * x11, red);
    float den = blk_reduce(x10 * x10 + x11 * x11, red);
    float largest = num / den;
    float* yp = y + (size_t)b * CC;
    yp[threadIdx.x] = b0 - largest * x10;
    yp[threadIdx.x + 256] = b1 - largest * x11;
    if (threadIdx.x == 0) acc[b * 8 + 0] = largest;
}

// dotwx = <w, x2>, den2 = <x2,x2>, x2 = y/||y||. w is partial [b][NSPLIT][512].
__global__ void k_fin2(const float* __restrict__ w, const float* __restrict__ y,
                       float* __restrict__ acc) {
    __shared__ float red[4];
    int b = blockIdx.x;
    const float* wp = w + (size_t)b * NSPLIT * CC;
    const float* yp = y + (size_t)b * CC;
    float w0 = 0.f, w1 = 0.f;
    for (int p = 0; p < NSPLIT; p++) {
        w0 += wp[p * CC + threadIdx.x];
        w1 += wp[p * CC + threadIdx.x + 256];
    }
    float y0 = yp[threadIdx.x], y1 = yp[threadIdx.x + 256];
    float ssy = blk_reduce(y0 * y0 + y1 * y1, red);
    float rn = 1.0f / fmaxf(sqrtf(ssy), FEPS);
    float x20 = y0 * rn, x21 = y1 * rn;
    float dotwx = blk_reduce(w0 * x20 + w1 * x21, red);
    float den2 = blk_reduce(x20 * x20 + x21 * x21, red);
    if (threadIdx.x == 0) { acc[b * 8 + 1] = dotwx; acc[b * 8 + 2] = den2; }
}

__global__ void k_out(const float* __restrict__ acc, float* __restrict__ out) {
    int b = threadIdx.x;                   // 64 threads = 1 wave
    float largest = acc[b * 8 + 0];
    float dotwx   = acc[b * 8 + 1];
    float den2    = acc[b * 8 + 2];
    float tmp = (dotwx - largest * den2) / den2;
    float smallest = tmp + largest;
    float r = largest / smallest - 1.0f;
    float pen = r * r;                     // BETA = 1
    for (int off = 32; off; off >>= 1) pen += __shfl_down(pen, off, 64);
    if (b == 0) out[0] = pen / (float)BB;
}

extern "C" void kernel_launch(void* const* d_in, const int* in_sizes, int n_in,
                              void* d_out, int out_size, void* d_ws, size_t ws_size,
                              hipStream_t stream) {
    const float* A  = (const float*)d_in[0];
    const float* x0 = (const float*)d_in[1];
    float* out = (float*)d_out;
    float* ws = (float*)d_ws;

    float* acc = ws;                          // 512 floats (64 x 8)
    float* Y   = ws + 512;                    // BB*CC dense y
    float* PA  = Y + BB * CC;                 // BB*NSPLIT*CC partials (2 MB)
    float* PB  = PA + (size_t)BB * NSPLIT * CC;
    float* T   = PB + (size_t)BB * NSPLIT * CC;   // BB*CC*DD = 102.8 MB
    const size_t need =
        ((size_t)512 + BB * CC + 2 * (size_t)BB * NSPLIT * CC +
         (size_t)BB * CC * DD) * sizeof(float);

    dim3 gS(NSPLIT, BB);
    if (ws_size >= need) {
        k_repack<<<dim3(56, BB), 256, 0, stream>>>(A, T);
        k_step<true><<<gS, 256, 0, stream>>>(T, x0, 1, PA);        // t1
        k_step<true><<<gS, 256, 0, stream>>>(T, PA, NSPLIT, PB);   // t2
        k_step<true><<<gS, 256, 0, stream>>>(T, PB, NSPLIT, PA);   // t3
        k_step<true><<<gS, 256, 0, stream>>>(T, PA, NSPLIT, PB);   // t4
        k_step<true><<<gS, 256, 0, stream>>>(T, PB, NSPLIT, PA);   // t5
        k_mid<<<BB, 256, 0, stream>>>(PB, PA, acc, Y);             // largest, y
        k_step<true><<<gS, 256, 0, stream>>>(T, Y, 1, PB);         // w = AAT x2
        k_fin2<<<BB, 256, 0, stream>>>(PB, Y, acc);
    } else {
        k_step<false><<<gS, 256, 0, stream>>>(A, x0, 1, PA);
        k_step<false><<<gS, 256, 0, stream>>>(A, PA, NSPLIT, PB);
        k_step<false><<<gS, 256, 0, stream>>>(A, PB, NSPLIT, PA);
        k_step<false><<<gS, 256, 0, stream>>>(A, PA, NSPLIT, PB);
        k_step<false><<<gS, 256, 0, stream>>>(A, PB, NSPLIT, PA);
        k_mid<<<BB, 256, 0, stream>>>(PB, PA, acc, Y);
        k_step<false><<<gS, 256, 0, stream>>>(A, Y, 1, PB);
        k_fin2<<<BB, 256, 0, stream>>>(PB, Y, acc);
    }
    k_out<<<1, 64, 0, stream>>>(acc, out);
}

// Round 7
// 388.851 us; speedup vs baseline: 1.1479x; 1.1479x over previous
//
#include <hip/hip_runtime.h>
#include <math.h>

// OFPenalty: power-iteration eigen-penalty on AAT = W W^T per batch, never
// materializing AAT. Round 9: R3's register pipeline at 3 blocks/CU.
//  - R6 post-mortem: launch_bounds(256,4) capped VGPR at 128 < the ~125-plus
//    live state of the two-buffer pipeline -> spill -> 60us/step. R3 (same
//    regs, lb(256,2)) ran 34us but was grid-starved (1.75 blocks/CU).
//  - This round: 768 blocks (12 slots x 64 b, 3/CU) with lb(256,3) (cap 170
//    VGPR, audited need ~125). Each wave owns quads q=(s*4+w)+48j, 4-5 iters,
//    two named register buffers, fully unrolled, ZERO barriers in the loop
//    (one for normalize, one for the final cross-wave v sum).
//  - Partials: 12 slots/batch -> workspace need 106.0 MB (< 107.1 MB proven
//    available in R6's run).
//  - k_repack unchanged (60us known; next target if this validates).
// A: (64, 512, 28, 28) fp32 -> W: (64, 512, 784). x0: (64, 512, 1).

#define BB 64
#define CC 512
#define DD 784
#define NSLOT 12        // k_step blocks per batch
#define NQ 196          // f4-columns (quads) total
#define F4PR 196        // float4 per row of A
#define BF4 100352      // float4 per batch matrix (512*784/4)
#define QT 28           // f4-cols per repack tile
#define CBS 12544       // f4 per cb slab = 196*64
#define FEPS 1e-12f

__device__ __forceinline__ float blk_reduce(float s, float* red) {
    for (int off = 32; off; off >>= 1) s += __shfl_down(s, off, 64);
    int w = threadIdx.x >> 6;
    if ((threadIdx.x & 63) == 0) red[w] = s;
    __syncthreads();
    float t = red[0] + red[1] + red[2] + red[3];
    __syncthreads();                       // allow red[] reuse by caller
    return t;
}

// Repack A[b][c][d] -> T3[b][cb][chq][i], c = cb*64+i, chq = d>>2 (0..195).
// (unchanged from R5; 60us known cost)
__global__ __launch_bounds__(256, 5)
void k_repack(const float* __restrict__ A, float* __restrict__ T) {
    __shared__ float4 lds4[64 * QT];       // 28,672 B
    const int tid = threadIdx.x;
    const int b = blockIdx.y, tile = blockIdx.x;
    const int cb = tile / 7, qt = tile % 7;
    const int R0 = cb * 64, q0 = qt * QT;
    const int r = tid >> 2, qg = tid & 3;
    const float4* src = (const float4*)A +
        ((size_t)b * CC + R0 + r) * F4PR + q0 + qg * 7;
    float4 a[7];
#pragma unroll
    for (int j = 0; j < 7; j++) a[j] = src[j];
    const int xr = (r >> 2) & 3;           // 2-bit XOR keeps chq' in 0..27
#pragma unroll
    for (int j = 0; j < 7; j++)
        lds4[r * QT + ((qg * 7 + j) ^ xr)] = a[j];
    __syncthreads();
    float4* dst = (float4*)T + (size_t)b * BF4 + (size_t)cb * CBS +
                  (size_t)q0 * 64;
#pragma unroll
    for (int j = 0; j < 7; j++) {
        int idx = j * 256 + tid;           // 0..1791 = 28 chq x 64 i
        int chq = idx >> 6, i = idx & 63;
        dst[idx] = lds4[i * QT + (chq ^ ((i >> 2) & 3))];
    }
}

// vout[b][s][c] = partial of (AAT_b * normalize(sum_p xin[b][p][:]))_c over
// wave-owned quads q = (s*4+w) + 48j, j = 0..3 (+j=4 for block s==0).
// Two named register buffers; loop fully unrolled; no barriers inside.
template <bool RP>
__global__ __launch_bounds__(256, 3)
void k_step(const float* __restrict__ M, const float* __restrict__ xin,
            const int nparts, float* __restrict__ vout) {
    __shared__ float xs[CC];
    __shared__ float vws[4][CC];
    __shared__ float red[4];

    const int tid = threadIdx.x;
    const int b = blockIdx.y, s = blockIdx.x;   // s in 0..11
    const int lane = tid & 63, w = tid >> 6;
    const int q0 = s * 4 + w;                   // 0..47
    const float4* Mb = (const float4*)M + (size_t)b * BF4;

    float xk[8];
    float vk[8] = {0.f, 0.f, 0.f, 0.f, 0.f, 0.f, 0.f, 0.f};

    auto loadq = [&](int q, float4* d) {
        if (RP) {
            const float4* g = Mb + (size_t)q * 64 + lane;
#pragma unroll
            for (int k = 0; k < 8; k++) d[k] = g[(size_t)k * CBS];
        } else {
            const float4* g = Mb + (size_t)lane * F4PR + q;
#pragma unroll
            for (int k = 0; k < 8; k++) d[k] = g[(size_t)64 * k * F4PR];
        }
    };
    auto computeq = [&](const float4* a) {
        float4 ua = make_float4(0.f, 0.f, 0.f, 0.f);
#pragma unroll
        for (int k = 0; k < 8; k++) {
            ua.x += a[k].x * xk[k]; ua.y += a[k].y * xk[k];
            ua.z += a[k].z * xk[k]; ua.w += a[k].w * xk[k];
        }
#pragma unroll
        for (int off = 1; off < 64; off <<= 1) {
            ua.x += __shfl_xor(ua.x, off, 64);
            ua.y += __shfl_xor(ua.y, off, 64);
            ua.z += __shfl_xor(ua.z, off, 64);
            ua.w += __shfl_xor(ua.w, off, 64);
        }
#pragma unroll
        for (int k = 0; k < 8; k++)
            vk[k] += a[k].x * ua.x + a[k].y * ua.y +
                     a[k].z * ua.z + a[k].w * ua.w;
    };

    // issue the first two quad tiles; their latency hides under phase A
    float4 ra[8], rb[8];
    loadq(q0, ra);
    loadq(q0 + 48, rb);

    // ---- phase A: normalize input (sum nparts partial segments)
    const float* xp = xin + (size_t)b * nparts * CC;
    float xv0 = 0.f, xv1 = 0.f;
    for (int p = 0; p < nparts; p++) {
        xv0 += xp[p * CC + tid];
        xv1 += xp[p * CC + tid + 256];
    }
    float ss = blk_reduce(xv0 * xv0 + xv1 * xv1, red);
    float rn = 1.0f / fmaxf(sqrtf(ss), FEPS);
    xs[tid] = xv0 * rn;
    xs[tid + 256] = xv1 * rn;
    __syncthreads();
#pragma unroll
    for (int k = 0; k < 8; k++) xk[k] = xs[lane + 64 * k];

    // ---- pipelined quad walk: compute(cur) overlaps the other buffer's loads
    computeq(ra);                           // q0
    loadq(q0 + 96, ra);
    computeq(rb);                           // q0+48
    loadq(q0 + 144, rb);
    const bool has5 = (q0 + 192) < NQ;      // true only for block s==0
    computeq(ra);                           // q0+96
    if (has5) loadq(q0 + 192, ra);
    computeq(rb);                           // q0+144
    if (has5) computeq(ra);                 // q0+192

    // ---- cross-wave quad sum (single barrier; waves re-sync here)
#pragma unroll
    for (int k = 0; k < 8; k++) vws[w][lane + 64 * k] = vk[k];
    __syncthreads();
    float* vp = vout + ((size_t)b * NSLOT + s) * CC;
    vp[tid]       = vws[0][tid] + vws[1][tid] + vws[2][tid] + vws[3][tid];
    vp[tid + 256] = vws[0][tid + 256] + vws[1][tid + 256] +
                    vws[2][tid + 256] + vws[3][tid + 256];
}

// largest_b = <t5, x1>/<x1,x1>, x1 = t4/||t4||;  y = t5 - largest*x1
// t4, t5 are NSLOT-way partial buffers [b][NSLOT][512].
__global__ void k_mid(const float* __restrict__ t4, const float* __restrict__ t5,
                      float* __restrict__ acc, float* __restrict__ y) {
    __shared__ float red[4];
    int b = blockIdx.x;
    const float* p4 = t4 + (size_t)b * NSLOT * CC;
    const float* p5 = t5 + (size_t)b * NSLOT * CC;
    float a0 = 0.f, a1 = 0.f, b0 = 0.f, b1 = 0.f;
    for (int p = 0; p < NSLOT; p++) {
        a0 += p4[p * CC + threadIdx.x]; a1 += p4[p * CC + threadIdx.x + 256];
        b0 += p5[p * CC + threadIdx.x]; b1 += p5[p * CC + threadIdx.x + 256];
    }
    float ss4 = blk_reduce(a0 * a0 + a1 * a1, red);
    float rn = 1.0f / fmaxf(sqrtf(ss4), FEPS);
    float x10 = a0 * rn, x11 = a1 * rn;
    float num = blk_reduce(b0 * x10 + b1 * x11, red);
    float den = blk_reduce(x10 * x10 + x11 * x11, red);
    float largest = num / den;
    float* yp = y + (size_t)b * CC;
    yp[threadIdx.x] = b0 - largest * x10;
    yp[threadIdx.x + 256] = b1 - largest * x11;
    if (threadIdx.x == 0) acc[b * 8 + 0] = largest;
}

// dotwx = <w, x2>, den2 = <x2,x2>, x2 = y/||y||. w is partial [b][NSLOT][512].
__global__ void k_fin2(const float* __restrict__ w, const float* __restrict__ y,
                       float* __restrict__ acc) {
    __shared__ float red[4];
    int b = blockIdx.x;
    const float* wp = w + (size_t)b * NSLOT * CC;
    const float* yp = y + (size_t)b * CC;
    float w0 = 0.f, w1 = 0.f;
    for (int p = 0; p < NSLOT; p++) {
        w0 += wp[p * CC + threadIdx.x];
        w1 += wp[p * CC + threadIdx.x + 256];
    }
    float y0 = yp[threadIdx.x], y1 = yp[threadIdx.x + 256];
    float ssy = blk_reduce(y0 * y0 + y1 * y1, red);
    float rn = 1.0f / fmaxf(sqrtf(ssy), FEPS);
    float x20 = y0 * rn, x21 = y1 * rn;
    float dotwx = blk_reduce(w0 * x20 + w1 * x21, red);
    float den2 = blk_reduce(x20 * x20 + x21 * x21, red);
    if (threadIdx.x == 0) { acc[b * 8 + 1] = dotwx; acc[b * 8 + 2] = den2; }
}

__global__ void k_out(const float* __restrict__ acc, float* __restrict__ out) {
    int b = threadIdx.x;                   // 64 threads = 1 wave
    float largest = acc[b * 8 + 0];
    float dotwx   = acc[b * 8 + 1];
    float den2    = acc[b * 8 + 2];
    float tmp = (dotwx - largest * den2) / den2;
    float smallest = tmp + largest;
    float r = largest / smallest - 1.0f;
    float pen = r * r;                     // BETA = 1
    for (int off = 32; off; off >>= 1) pen += __shfl_down(pen, off, 64);
    if (b == 0) out[0] = pen / (float)BB;
}

extern "C" void kernel_launch(void* const* d_in, const int* in_sizes, int n_in,
                              void* d_out, int out_size, void* d_ws, size_t ws_size,
                              hipStream_t stream) {
    const float* A  = (const float*)d_in[0];
    const float* x0 = (const float*)d_in[1];
    float* out = (float*)d_out;
    float* ws = (float*)d_ws;

    float* acc = ws;                          // 512 floats (64 x 8)
    float* Y   = ws + 512;                    // BB*CC dense y
    float* PA  = Y + BB * CC;                 // BB*NSLOT*CC partials (1.5 MB)
    float* PB  = PA + (size_t)BB * NSLOT * CC;
    float* T   = PB + (size_t)BB * NSLOT * CC;   // BB*CC*DD = 102.8 MB
    const size_t need =
        ((size_t)512 + BB * CC + 2 * (size_t)BB * NSLOT * CC +
         (size_t)BB * CC * DD) * sizeof(float);

    dim3 gS(NSLOT, BB);
    if (ws_size >= need) {
        k_repack<<<dim3(56, BB), 256, 0, stream>>>(A, T);
        k_step<true><<<gS, 256, 0, stream>>>(T, x0, 1, PA);       // t1
        k_step<true><<<gS, 256, 0, stream>>>(T, PA, NSLOT, PB);   // t2
        k_step<true><<<gS, 256, 0, stream>>>(T, PB, NSLOT, PA);   // t3
        k_step<true><<<gS, 256, 0, stream>>>(T, PA, NSLOT, PB);   // t4
        k_step<true><<<gS, 256, 0, stream>>>(T, PB, NSLOT, PA);   // t5
        k_mid<<<BB, 256, 0, stream>>>(PB, PA, acc, Y);            // largest, y
        k_step<true><<<gS, 256, 0, stream>>>(T, Y, 1, PB);        // w = AAT x2
        k_fin2<<<BB, 256, 0, stream>>>(PB, Y, acc);
    } else {
        k_step<false><<<gS, 256, 0, stream>>>(A, x0, 1, PA);
        k_step<false><<<gS, 256, 0, stream>>>(A, PA, NSLOT, PB);
        k_step<false><<<gS, 256, 0, stream>>>(A, PB, NSLOT, PA);
        k_step<false><<<gS, 256, 0, stream>>>(A, PA, NSLOT, PB);
        k_step<false><<<gS, 256, 0, stream>>>(A, PB, NSLOT, PA);
        k_mid<<<BB, 256, 0, stream>>>(PB, PA, acc, Y);
        k_step<false><<<gS, 256, 0, stream>>>(A, Y, 1, PB);
        k_fin2<<<BB, 256, 0, stream>>>(PB, Y, acc);
    }
    k_out<<<1, 64, 0, stream>>>(acc, out);
}

// Round 8
// 283.780 us; speedup vs baseline: 1.5729x; 1.3703x over previous
//
#include <hip/hip_runtime.h>
#include <math.h>

// OFPenalty: power-iteration eigen-penalty on AAT = W W^T per batch, never
// materializing AAT. Round 10: R3 (274us, proven best) + NONTEMPORAL reads.
//  - Seven structural variants all pin at 2.4-3.1 TB/s effective read while
//    write-only fill = 6.9 TB/s and cold-HBM copy = 6.3 TB/s. Shared factor:
//    our 103MB working set is L3-resident -> all reads ride the L3-hit path.
//    Theory: L3-hit read BW ~3 TB/s < HBM streaming on this part.
//  - Change vs R3 (exactly one): k_step's T reads use
//    __builtin_nontemporal_load (nt bit -> read-around L2/L3, stream HBM).
//    Tell-tale: per-step FETCH_SIZE should RISE to ~103MB; dur 34 -> ~20us.
//  - Everything else byte-identical to the 274us kernel (T2 layout
//    [b][chq][c], NSPLIT=7, 7 quads/wave register pipeline, lb(256,2)).
// A: (64, 512, 28, 28) fp32 -> W: (64, 512, 784). x0: (64, 512, 1).

#define BB 64
#define CC 512
#define DD 784
#define DCH 16
#define NSPLIT 7
#define NCHPS 7         // chunks per split; NSPLIT*NCHPS = 49 = DD/DCH
#define F4PR 196        // float4 per row of A
#define BF4 100352      // float4 per batch matrix (512*784/4)
#define FEPS 1e-12f

typedef float f4v __attribute__((ext_vector_type(4)));

__device__ __forceinline__ void gload16(const float4* gp, float4* lp) {
    __builtin_amdgcn_global_load_lds(
        (const __attribute__((address_space(1))) void*)gp,
        (__attribute__((address_space(3))) void*)lp, 16, 0, 0);
}

__device__ __forceinline__ float blk_reduce(float s, float* red) {
    for (int off = 32; off; off >>= 1) s += __shfl_down(s, off, 64);
    int w = threadIdx.x >> 6;
    if ((threadIdx.x & 63) == 0) red[w] = s;
    __syncthreads();
    float t = red[0] + red[1] + red[2] + red[3];
    __syncthreads();                       // allow red[] reuse by caller
    return t;
}

// Repack A[b][c][d] -> T2[b][chq][c][dq], chq=d>>2 (0..195).
// Block = (rowblock of 16 c, b). Stage 16 full rows in LDS (50 KB, linear,
// global_load_lds), then write: each chq gets 16 c x 16B = 256B contiguous
// global segments. (unchanged from the 274us run)
__global__ __launch_bounds__(256, 3)
void k_repack(const float* __restrict__ A, float* __restrict__ T) {
    __shared__ float4 lds4[16 * F4PR];     // 3136 f4 = 50,176 B
    const int tid = threadIdx.x, lane = tid & 63, w = tid >> 6;
    const int b = blockIdx.y, c0 = blockIdx.x * 16;
    const float4* src4 = (const float4*)A + ((size_t)b * CC + c0) * F4PR;
#pragma unroll
    for (int i = 0; i < 12; i++)
        gload16(src4 + i * 256 + w * 64 + lane, lds4 + i * 256 + w * 64);
    if (w == 0) gload16(src4 + 3072 + lane, lds4 + 3072);
    __syncthreads();                        // drains vmcnt before barrier
    float4* dst4 = (float4*)T + (size_t)b * BF4;
#pragma unroll
    for (int j = 0; j < 13; j++) {
        int idx = j * 256 + tid;
        if (idx < 3136) {
            int chq = idx >> 4, i = idx & 15;     // chq in 0..195
            dst4[(size_t)chq * CC + c0 + i] = lds4[i * F4PR + chq];
        }
    }
}

// vout[b][s][c] = partial of (AAT_b * normalize(sum_p xin[b][p][:]))_c over
// chunks ch = s*7 .. s*7+6. RP: quad-major T2 with NONTEMPORAL loads; else A
// directly (strided fallback). Wave w owns quad w of each chunk; lane owns
// rows c = lane + 64k.
template <bool RP>
__global__ __launch_bounds__(256, 2)
void k_step(const float* __restrict__ M, const float* __restrict__ xin,
            const int nparts, float* __restrict__ vout) {
    __shared__ float xs[CC];
    __shared__ float vws[4][CC];
    __shared__ float red[4];

    const int tid = threadIdx.x;
    const int b = blockIdx.y, s = blockIdx.x;
    const int lane = tid & 63, w = tid >> 6;
    const float4* Mb = (const float4*)M + (size_t)b * BF4;

    // ---- phase A: normalize input (sum nparts partial segments)
    const float* xp = xin + (size_t)b * nparts * CC;
    float xv0 = 0.f, xv1 = 0.f;
    for (int p = 0; p < nparts; p++) {
        xv0 += xp[p * CC + tid];
        xv1 += xp[p * CC + tid + 256];
    }
    float ss = blk_reduce(xv0 * xv0 + xv1 * xv1, red);
    float rn = 1.0f / fmaxf(sqrtf(ss), FEPS);
    xs[tid] = xv0 * rn;
    xs[tid + 256] = xv1 * rn;
    __syncthreads();

    float xk[8];
#pragma unroll
    for (int k = 0; k < 8; k++) xk[k] = xs[lane + 64 * k];

    const int ch0 = s * NCHPS;
    f4v a[2][8];
    float vk[8] = {0.f, 0.f, 0.f, 0.f, 0.f, 0.f, 0.f, 0.f};

    auto load = [&](int ch, f4v* dst) {
        if (RP) {
            const f4v* g = (const f4v*)(Mb + (size_t)(ch * 4 + w) * CC + lane);
#pragma unroll
            for (int k = 0; k < 8; k++)
                dst[k] = __builtin_nontemporal_load(g + 64 * k);
        } else {
            const f4v* g = (const f4v*)(Mb + (size_t)lane * F4PR + ch * 4 + w);
#pragma unroll
            for (int k = 0; k < 8; k++) dst[k] = g[(size_t)64 * k * F4PR];
        }
    };

    load(ch0, a[0]);
#pragma unroll
    for (int j = 0; j < NCHPS; j++) {
        const int cb = j & 1;                      // static after full unroll
        if (j + 1 < NCHPS) load(ch0 + j + 1, a[cb ^ 1]);

        // u-phase: u4[dq] = sum_c A[c][ch*16+w*4+dq] * xhat[c]
        f4v ua = {0.f, 0.f, 0.f, 0.f};
#pragma unroll
        for (int k = 0; k < 8; k++) {
            ua.x += a[cb][k].x * xk[k]; ua.y += a[cb][k].y * xk[k];
            ua.z += a[cb][k].z * xk[k]; ua.w += a[cb][k].w * xk[k];
        }
#pragma unroll
        for (int off = 1; off < 64; off <<= 1) {
            ua.x += __shfl_xor(ua.x, off, 64);
            ua.y += __shfl_xor(ua.y, off, 64);
            ua.z += __shfl_xor(ua.z, off, 64);
            ua.w += __shfl_xor(ua.w, off, 64);
        }

        // v-phase: vk[k] += A[c][quad] . u4, accumulated across chunks
#pragma unroll
        for (int k = 0; k < 8; k++)
            vk[k] += a[cb][k].x * ua.x + a[cb][k].y * ua.y +
                     a[cb][k].z * ua.z + a[cb][k].w * ua.w;
    }

    // ---- cross-wave v reduction (quads 0..3 live on waves 0..3)
#pragma unroll
    for (int k = 0; k < 8; k++) vws[w][lane + 64 * k] = vk[k];
    __syncthreads();
    float* vp = vout + ((size_t)b * NSPLIT + s) * CC;
    vp[tid]       = vws[0][tid] + vws[1][tid] + vws[2][tid] + vws[3][tid];
    vp[tid + 256] = vws[0][tid + 256] + vws[1][tid + 256] +
                    vws[2][tid + 256] + vws[3][tid + 256];
}

// largest_b = <t5, x1>/<x1,x1>, x1 = t4/||t4||;  y = t5 - largest*x1
// t4, t5 are 7-way partial buffers [b][7][512].
__global__ void k_mid(const float* __restrict__ t4, const float* __restrict__ t5,
                      float* __restrict__ acc, float* __restrict__ y) {
    __shared__ float red[4];
    int b = blockIdx.x;
    const float* p4 = t4 + (size_t)b * NSPLIT * CC;
    const float* p5 = t5 + (size_t)b * NSPLIT * CC;
    float a0 = 0.f, a1 = 0.f, b0 = 0.f, b1 = 0.f;
    for (int p = 0; p < NSPLIT; p++) {
        a0 += p4[p * CC + threadIdx.x]; a1 += p4[p * CC + threadIdx.x + 256];
        b0 += p5[p * CC + threadIdx.x]; b1 += p5[p * CC + threadIdx.x + 256];
    }
    float ss4 = blk_reduce(a0 * a0 + a1 * a1, red);
    float rn = 1.0f / fmaxf(sqrtf(ss4), FEPS);
    float x10 = a0 * rn, x11 = a1 * rn;
    float num = blk_reduce(b0 * x10 + b1 * x11, red);
    float den = blk_reduce(x10 * x10 + x11 * x11, red);
    float largest = num / den;
    float* yp = y + (size_t)b * CC;
    yp[threadIdx.x] = b0 - largest * x10;
    yp[threadIdx.x + 256] = b1 - largest * x11;
    if (threadIdx.x == 0) acc[b * 8 + 0] = largest;
}

// dotwx = <w, x2>, den2 = <x2,x2>, x2 = y/||y||. w is partial [b][7][512].
__global__ void k_fin2(const float* __restrict__ w, const float* __restrict__ y,
                       float* __restrict__ acc) {
    __shared__ float red[4];
    int b = blockIdx.x;
    const float* wp = w + (size_t)b * NSPLIT * CC;
    const float* yp = y + (size_t)b * CC;
    float w0 = 0.f, w1 = 0.f;
    for (int p = 0; p < NSPLIT; p++) {
        w0 += wp[p * CC + threadIdx.x];
        w1 += wp[p * CC + threadIdx.x + 256];
    }
    float y0 = yp[threadIdx.x], y1 = yp[threadIdx.x + 256];
    float ssy = blk_reduce(y0 * y0 + y1 * y1, red);
    float rn = 1.0f / fmaxf(sqrtf(ssy), FEPS);
    float x20 = y0 * rn, x21 = y1 * rn;
    float dotwx = blk_reduce(w0 * x20 + w1 * x21, red);
    float den2 = blk_reduce(x20 * x20 + x21 * x21, red);
    if (threadIdx.x == 0) { acc[b * 8 + 1] = dotwx; acc[b * 8 + 2] = den2; }
}

__global__ void k_out(const float* __restrict__ acc, float* __restrict__ out) {
    int b = threadIdx.x;                   // 64 threads = 1 wave
    float largest = acc[b * 8 + 0];
    float dotwx   = acc[b * 8 + 1];
    float den2    = acc[b * 8 + 2];
    float tmp = (dotwx - largest * den2) / den2;
    float smallest = tmp + largest;
    float r = largest / smallest - 1.0f;
    float pen = r * r;                     // BETA = 1
    for (int off = 32; off; off >>= 1) pen += __shfl_down(pen, off, 64);
    if (b == 0) out[0] = pen / (float)BB;
}

extern "C" void kernel_launch(void* const* d_in, const int* in_sizes, int n_in,
                              void* d_out, int out_size, void* d_ws, size_t ws_size,
                              hipStream_t stream) {
    const float* A  = (const float*)d_in[0];
    const float* x0 = (const float*)d_in[1];
    float* out = (float*)d_out;
    float* ws = (float*)d_ws;

    float* acc = ws;                          // 512 floats (64 x 8)
    float* Y   = ws + 512;                    // BB*CC dense y
    float* PA  = Y + BB * CC;                 // BB*NSPLIT*CC partials
    float* PB  = PA + (size_t)BB * NSPLIT * CC;
    float* T   = PB + (size_t)BB * NSPLIT * CC;   // BB*CC*DD = 102.8 MB
    const size_t need =
        ((size_t)512 + BB * CC + 2 * (size_t)BB * NSPLIT * CC +
         (size_t)BB * CC * DD) * sizeof(float);

    dim3 gS(NSPLIT, BB);
    if (ws_size >= need) {
        k_repack<<<dim3(32, BB), 256, 0, stream>>>(A, T);
        k_step<true><<<gS, 256, 0, stream>>>(T, x0, 1, PA);        // t1
        k_step<true><<<gS, 256, 0, stream>>>(T, PA, NSPLIT, PB);   // t2
        k_step<true><<<gS, 256, 0, stream>>>(T, PB, NSPLIT, PA);   // t3
        k_step<true><<<gS, 256, 0, stream>>>(T, PA, NSPLIT, PB);   // t4
        k_step<true><<<gS, 256, 0, stream>>>(T, PB, NSPLIT, PA);   // t5
        k_mid<<<BB, 256, 0, stream>>>(PB, PA, acc, Y);             // largest, y
        k_step<true><<<gS, 256, 0, stream>>>(T, Y, 1, PB);         // w
        k_fin2<<<BB, 256, 0, stream>>>(PB, Y, acc);
    } else {
        k_step<false><<<gS, 256, 0, stream>>>(A, x0, 1, PA);
        k_step<false><<<gS, 256, 0, stream>>>(A, PA, NSPLIT, PB);
        k_step<false><<<gS, 256, 0, stream>>>(A, PB, NSPLIT, PA);
        k_step<false><<<gS, 256, 0, stream>>>(A, PA, NSPLIT, PB);
        k_step<false><<<gS, 256, 0, stream>>>(A, PB, NSPLIT, PA);
        k_mid<<<BB, 256, 0, stream>>>(PB, PA, acc, Y);
        k_step<false><<<gS, 256, 0, stream>>>(A, Y, 1, PB);
        k_fin2<<<BB, 256, 0, stream>>>(PB, Y, acc);
    }
    k_out<<<1, 64, 0, stream>>>(acc, out);
}